// Round 10
// baseline (509.204 us; speedup 1.0000x reference)
//
#include <hip/hip_runtime.h>

#define N_NODES 100000
#define NPAD    100096      // multiple of 128 so layer blocks need no row clamp
#define N_EDGES 1600000
#define FDIM 128
#define GDIM 64
#define CDIM 10

#define BSH   9
#define BSIZE 512           // nodes per bucket (r5-proven config)
#define NB    196           // ceil(N_NODES / BSIZE)
#define EPB   8192          // edges per block in bucket passes -> 196 blocks

typedef unsigned short us16;
typedef us16 usx4 __attribute__((ext_vector_type(4)));
typedef us16 usx8 __attribute__((ext_vector_type(8)));
typedef short bfrag __attribute__((ext_vector_type(8)));   // 8 bf16 = 4 VGPRs
typedef float f32x4 __attribute__((ext_vector_type(4)));

__device__ __forceinline__ float bf2f(us16 u) {
  return __uint_as_float(((unsigned)u) << 16);
}
__device__ __forceinline__ us16 f2bf(float f) {
  unsigned u = __float_as_uint(f);
  u += 0x7FFFu + ((u >> 16) & 1u);   // RNE
  return (us16)(u >> 16);
}

// ---------------- prep: cast x, pack W, zero pooled, bucket histogram ---------
// bcnt is zeroed by a memsetAsync BEFORE this kernel, so the bhist blocks here
// (independent of the cast/pack blocks) can atomicAdd safely.
#define XB 6250            // N_NODES*FDIM/8/256 cast blocks
__global__ __launch_bounds__(256) void k_prep(
    const float* __restrict__ x, us16* __restrict__ xb,
    const float* __restrict__ Wrel1, const float* __restrict__ Wroot1,
    const float* __restrict__ Wrel2, const float* __restrict__ Wroot2,
    const float* __restrict__ Wrel3, const float* __restrict__ Wroot3,
    us16* __restrict__ Wp, float* __restrict__ pooled,
    const int* __restrict__ edst, int* __restrict__ bcnt) {
  int bx = blockIdx.x, tid = threadIdx.x;
  if (bx < XB) {
    size_t i = ((size_t)bx * 256 + tid) * 8;    // 8 floats per thread
    float4 a = *(const float4*)(x + i);
    float4 b = *(const float4*)(x + i + 4);
    usx8 o;
    o[0]=f2bf(a.x); o[1]=f2bf(a.y); o[2]=f2bf(a.z); o[3]=f2bf(a.w);
    o[4]=f2bf(b.x); o[5]=f2bf(b.y); o[6]=f2bf(b.z); o[7]=f2bf(b.w);
    *(usx8*)(xb + i) = o;
  } else if (bx < XB + 384) {
    int wb = bx - XB;             // 0..383
    int l = wb >> 7;              // layer
    const float* Wrel  = (l == 0) ? Wrel1  : (l == 1) ? Wrel2  : Wrel3;
    const float* Wroot = (l == 0) ? Wroot1 : (l == 1) ? Wroot2 : Wroot3;
    int idx = (wb & 127) * 256 + tid;   // 0..32767
    int k = idx >> 7;       // 0..255
    int c = idx & 127;      // output col
    float v = (k < 128) ? Wrel[c * 128 + k] : Wroot[c * 128 + k - 128];
    Wp[(size_t)l * 32768 + (((k >> 3) * 128 + c) << 3) + (k & 7)] = f2bf(v);
  } else if (bx == XB + 384) {
    for (int i = tid; i < GDIM * FDIM; i += 256) pooled[i] = 0.f;
  } else {
    // bucket histogram over edge chunk
    __shared__ int h[NB];
    int cb = bx - (XB + 385);
    for (int i = tid; i < NB; i += 256) h[i] = 0;
    __syncthreads();
    int s0 = cb * EPB;
    int e0 = s0 + EPB; if (e0 > N_EDGES) e0 = N_EDGES;
    for (int i = s0 + tid; i < e0; i += 256) atomicAdd(&h[edst[i] >> BSH], 1);
    __syncthreads();
    for (int i = tid; i < NB; i += 256)
      if (h[i]) atomicAdd(&bcnt[i], h[i]);
  }
}

// scan NB bucket counts -> offsets + cursors (single block)
__global__ void k_bscan(const int* __restrict__ bcnt, int* __restrict__ boff,
                        int* __restrict__ bcursor, int* __restrict__ row_ptr) {
  __shared__ int sm[256];
  int tid = threadIdx.x;
  int v = (tid < NB) ? bcnt[tid] : 0;
  sm[tid] = v;
  __syncthreads();
  for (int off = 1; off < 256; off <<= 1) {
    int t = (tid >= off) ? sm[tid - off] : 0;
    __syncthreads();
    sm[tid] += t;
    __syncthreads();
  }
  if (tid < NB) { int ex = sm[tid] - v; boff[tid] = ex; bcursor[tid] = ex; }
  if (tid == 0) { boff[NB] = N_EDGES; row_ptr[N_NODES] = N_EDGES; }
}

// Pass C: counting-sort edges into bucket-contiguous runs.
// Record packed as (src << 9) | dst_local  (src < 2^17 -> fits 26 bits).
__global__ __launch_bounds__(256) void k_bscatter(
    const int* __restrict__ src, const int* __restrict__ dst,
    int* __restrict__ bcursor, int* __restrict__ ebuf) {
  __shared__ int h[NB];
  __shared__ int base[NB];
  __shared__ int lc[NB];
  int tid = threadIdx.x;
  for (int i = tid; i < NB; i += 256) h[i] = 0;
  __syncthreads();
  int s0 = blockIdx.x * EPB;
  int e0 = s0 + EPB; if (e0 > N_EDGES) e0 = N_EDGES;
  for (int i = s0 + tid; i < e0; i += 256) atomicAdd(&h[dst[i] >> BSH], 1);
  __syncthreads();
  for (int i = tid; i < NB; i += 256) {
    base[i] = h[i] ? atomicAdd(&bcursor[i], h[i]) : 0;
    lc[i] = 0;
  }
  __syncthreads();
  for (int i = s0 + tid; i < e0; i += 256) {
    int d = dst[i];
    int b = d >> BSH;
    int lp = atomicAdd(&lc[b], 1);
    ebuf[base[b] + lp] = (src[i] << BSH) | (d & (BSIZE - 1));
  }
}

// Pass D: per-bucket histogram + Blelloch scan -> row_ptr, LDS-cursor scatter.
__global__ __launch_bounds__(256) void k_bucket_csr(
    const int* __restrict__ ebuf, const int* __restrict__ boff,
    int* __restrict__ row_ptr, int* __restrict__ csr_src) {
  __shared__ int hist[BSIZE];
  __shared__ int cur[BSIZE];
  int b = blockIdx.x, tid = threadIdx.x;
  int eoff = boff[b], ecnt = boff[b + 1] - eoff;
  int base = b * BSIZE;
  hist[tid] = 0; hist[tid + 256] = 0;
  __syncthreads();
  for (int i = tid; i < ecnt; i += 256)
    atomicAdd(&hist[ebuf[eoff + i] & (BSIZE - 1)], 1);
  __syncthreads();
  for (int d = 1; d < BSIZE; d <<= 1) {
    int idx = (tid + 1) * (d << 1) - 1;
    if (idx < BSIZE) hist[idx] += hist[idx - d];
    __syncthreads();
  }
  if (tid == 0) hist[BSIZE - 1] = 0;
  __syncthreads();
  for (int d = BSIZE >> 1; d >= 1; d >>= 1) {
    int idx = (tid + 1) * (d << 1) - 1;
    if (idx < BSIZE) {
      int t = hist[idx - d];
      hist[idx - d] = hist[idx];
      hist[idx] += t;
    }
    __syncthreads();
  }
  {
    int n0 = base + tid, n1 = base + tid + 256;
    if (n0 < N_NODES) row_ptr[n0] = eoff + hist[tid];
    if (n1 < N_NODES) row_ptr[n1] = eoff + hist[tid + 256];
    cur[tid] = hist[tid];
    cur[tid + 256] = hist[tid + 256];
  }
  __syncthreads();
  for (int i = tid; i < ecnt; i += 256) {
    int e = ebuf[eoff + i];
    int lp = atomicAdd(&cur[e & (BSIZE - 1)], 1);
    csr_src[eoff + lp] = e >> BSH;
  }
}

// ---------------- fused layer: gather-aggregate -> MFMA dual GEMM -------------
// out = relu(agg(hin) @ Wrel^T + hin @ Wroot^T + b).
// 512 threads / 128 rows per block: LDS 34.8 KB + 48 VGPR -> 4 blocks/CU
// = 32 waves/CU (vs 12 at 256 threads) for gather-latency concurrency.
#define ASTR 136
#define LROWS 128
__global__ __launch_bounds__(512) void k_layer(
    const us16* __restrict__ hin, const us16* __restrict__ Wp,
    const float* __restrict__ bias, const int* __restrict__ row_ptr,
    const int* __restrict__ csr_src, us16* __restrict__ out) {
  __shared__ us16 As[LROWS * ASTR];   // 34.8 KB
  int tid = threadIdx.x;
  int node0 = blockIdx.x * LROWS;
  int slot = tid >> 4;      // 0..31: node slot within round
  int lane16 = tid & 15;    // feature octet
  const us16* gbase = hin + lane16 * 8;

  // ---- phase 1: aggregate 128 nodes (4 rounds x 32 concurrent) ----
#pragma unroll 1
  for (int rnd = 0; rnd < 4; ++rnd) {
    int node = node0 + rnd * 32 + slot;
    float a0 = 0.f, a1 = 0.f, a2 = 0.f, a3 = 0.f;
    float a4 = 0.f, a5 = 0.f, a6 = 0.f, a7 = 0.f;
    if (node < N_NODES) {
      int s = row_ptr[node], e = row_ptr[node + 1];
      int p = s;
      for (; p + 4 <= e; p += 4) {
        int j0 = csr_src[p], j1 = csr_src[p + 1];
        int j2 = csr_src[p + 2], j3 = csr_src[p + 3];
        usx8 v0 = *(const usx8*)(gbase + (size_t)j0 * FDIM);
        usx8 v1 = *(const usx8*)(gbase + (size_t)j1 * FDIM);
        usx8 v2 = *(const usx8*)(gbase + (size_t)j2 * FDIM);
        usx8 v3 = *(const usx8*)(gbase + (size_t)j3 * FDIM);
        a0 += bf2f(v0[0]) + bf2f(v1[0]) + bf2f(v2[0]) + bf2f(v3[0]);
        a1 += bf2f(v0[1]) + bf2f(v1[1]) + bf2f(v2[1]) + bf2f(v3[1]);
        a2 += bf2f(v0[2]) + bf2f(v1[2]) + bf2f(v2[2]) + bf2f(v3[2]);
        a3 += bf2f(v0[3]) + bf2f(v1[3]) + bf2f(v2[3]) + bf2f(v3[3]);
        a4 += bf2f(v0[4]) + bf2f(v1[4]) + bf2f(v2[4]) + bf2f(v3[4]);
        a5 += bf2f(v0[5]) + bf2f(v1[5]) + bf2f(v2[5]) + bf2f(v3[5]);
        a6 += bf2f(v0[6]) + bf2f(v1[6]) + bf2f(v2[6]) + bf2f(v3[6]);
        a7 += bf2f(v0[7]) + bf2f(v1[7]) + bf2f(v2[7]) + bf2f(v3[7]);
      }
      for (; p < e; ++p) {
        int j = csr_src[p];
        usx8 v = *(const usx8*)(gbase + (size_t)j * FDIM);
        a0 += bf2f(v[0]); a1 += bf2f(v[1]); a2 += bf2f(v[2]); a3 += bf2f(v[3]);
        a4 += bf2f(v[4]); a5 += bf2f(v[5]); a6 += bf2f(v[6]); a7 += bf2f(v[7]);
      }
    }
    usx8 o;
    o[0] = f2bf(a0); o[1] = f2bf(a1); o[2] = f2bf(a2); o[3] = f2bf(a3);
    o[4] = f2bf(a4); o[5] = f2bf(a5); o[6] = f2bf(a6); o[7] = f2bf(a7);
    *(usx8*)&As[(rnd * 32 + slot) * ASTR + lane16 * 8] = o;
  }
  __syncthreads();

  // ---- phase 2: MFMA.  A agg-half from LDS, root-half from global (own rows),
  //      W b-frags straight from L1/L2.
  int wave = tid >> 6, lane = tid & 63;
  int m = lane & 15, quad = lane >> 4;
  size_t rowA = (size_t)(node0 + wave * 16 + m);
  const us16* baseH = hin + rowA * FDIM + quad * 8;
  const us16* aldsb = &As[(wave * 16 + m) * ASTR + quad * 8];
  f32x4 acc[8];
#pragma unroll
  for (int t = 0; t < 8; ++t) acc[t] = (f32x4){0.f, 0.f, 0.f, 0.f};

#pragma unroll 1
  for (int c = 0; c < 8; ++c) {
    bfrag a;
    if (c < 4) a = *(const bfrag*)(aldsb + c * 32);
    else       a = *(const bfrag*)(baseH + (c - 4) * 32);
    int kq = c * 4 + quad;
    const us16* wbase = Wp + (((size_t)kq * 128 + m) << 3);
#pragma unroll
    for (int t = 0; t < 8; ++t) {
      bfrag b = *(const bfrag*)(wbase + t * 128);   // 16 cols * 8 j
      acc[t] = __builtin_amdgcn_mfma_f32_16x16x32_bf16(a, b, acc[t], 0, 0, 0);
    }
  }
  // epilogue: D lane mapping col = lane&15, row = quad*4 + i
  int orow0 = node0 + wave * 16 + quad * 4;
#pragma unroll
  for (int t = 0; t < 8; ++t) {
    int col = t * 16 + m;
    float bv = bias[col];
#pragma unroll
    for (int i = 0; i < 4; ++i) {
      int r = orow0 + i;
      if (r < N_NODES)
        out[(size_t)r * FDIM + col] = f2bf(fmaxf(acc[t][i] + bv, 0.f));
    }
  }
}

// ---------------- global mean pool phase 1 (bf16 16B loads, fp32 atomics) -----
#define POOL_CHUNK 256
__global__ __launch_bounds__(256) void k_pool_partial(
    const us16* __restrict__ h, const int* __restrict__ batch,
    float* __restrict__ pooled) {
  int start = blockIdx.x * POOL_CHUNK;
  int end = start + POOL_CHUNK;
  if (end > N_NODES) end = N_NODES;
  int lane16 = threadIdx.x & 15;
  int slot = threadIdx.x >> 4;   // 0..15
  int f = lane16 * 8;
  float a0 = 0.f, a1 = 0.f, a2 = 0.f, a3 = 0.f;
  float a4 = 0.f, a5 = 0.f, a6 = 0.f, a7 = 0.f;
  int gcur = -1;
  for (int i = start + slot; i < end; i += 16) {
    int g = batch[i];
    usx8 v = *(const usx8*)(h + (size_t)i * FDIM + f);
    if (g != gcur) {
      if (gcur >= 0) {
        float* p = pooled + (size_t)gcur * FDIM + f;
        atomicAdd(p + 0, a0); atomicAdd(p + 1, a1);
        atomicAdd(p + 2, a2); atomicAdd(p + 3, a3);
        atomicAdd(p + 4, a4); atomicAdd(p + 5, a5);
        atomicAdd(p + 6, a6); atomicAdd(p + 7, a7);
      }
      a0 = a1 = a2 = a3 = a4 = a5 = a6 = a7 = 0.f;
      gcur = g;
    }
    a0 += bf2f(v[0]); a1 += bf2f(v[1]); a2 += bf2f(v[2]); a3 += bf2f(v[3]);
    a4 += bf2f(v[4]); a5 += bf2f(v[5]); a6 += bf2f(v[6]); a7 += bf2f(v[7]);
  }
  if (gcur >= 0) {
    float* p = pooled + (size_t)gcur * FDIM + f;
    atomicAdd(p + 0, a0); atomicAdd(p + 1, a1);
    atomicAdd(p + 2, a2); atomicAdd(p + 3, a3);
    atomicAdd(p + 4, a4); atomicAdd(p + 5, a5);
    atomicAdd(p + 6, a6); atomicAdd(p + 7, a7);
  }
}

// ---------------- MLP head + log_softmax ----------------
__global__ __launch_bounds__(128) void k_head(
    const float* __restrict__ pooled, const int* __restrict__ batch,
    const float* __restrict__ Wl1, const float* __restrict__ bl1,
    const float* __restrict__ Wl2, const float* __restrict__ bl2,
    float* __restrict__ out) {
  int g = blockIdx.x;
  __shared__ int sb[2];
  __shared__ float p[128];
  __shared__ float h1[64];
  __shared__ float logit[CDIM];
  if (threadIdx.x < 2) {
    int key = g + (int)threadIdx.x;
    int lo = 0, hi = N_NODES;
    while (lo < hi) {
      int mid = (lo + hi) >> 1;
      if (batch[mid] < key) lo = mid + 1; else hi = mid;
    }
    sb[threadIdx.x] = lo;
  }
  __syncthreads();
  float cnt = (float)(sb[1] - sb[0]);
  p[threadIdx.x] = pooled[g * FDIM + threadIdx.x] / fmaxf(cnt, 1.f);
  __syncthreads();
  if (threadIdx.x < 64) {
    float acc = bl1[threadIdx.x];
    for (int k = 0; k < 128; ++k) acc += p[k] * Wl1[threadIdx.x * 128 + k];
    h1[threadIdx.x] = fmaxf(acc, 0.f);
  }
  __syncthreads();
  if (threadIdx.x < CDIM) {
    float acc = bl2[threadIdx.x];
    for (int k = 0; k < 64; ++k) acc += h1[k] * Wl2[threadIdx.x * 64 + k];
    logit[threadIdx.x] = acc;
  }
  __syncthreads();
  if (threadIdx.x == 0) {
    float m = -1e30f;
    for (int c = 0; c < CDIM; ++c) m = fmaxf(m, logit[c]);
    float s = 0.f;
    for (int c = 0; c < CDIM; ++c) s += expf(logit[c] - m);
    float ls = logf(s);
    for (int c = 0; c < CDIM; ++c) out[g * CDIM + c] = logit[c] - m - ls;
  }
}

extern "C" void kernel_launch(void* const* d_in, const int* in_sizes, int n_in,
                              void* d_out, int out_size, void* d_ws, size_t ws_size,
                              hipStream_t stream) {
  const float* x      = (const float*)d_in[0];
  const int* edge_idx = (const int*)d_in[1];
  const int* batch    = (const int*)d_in[2];
  const float* W1_rel  = (const float*)d_in[4];
  const float* b1_rel  = (const float*)d_in[5];
  const float* W1_root = (const float*)d_in[6];
  const float* W2_rel  = (const float*)d_in[7];
  const float* b2_rel  = (const float*)d_in[8];
  const float* W2_root = (const float*)d_in[9];
  const float* W3_rel  = (const float*)d_in[10];
  const float* b3_rel  = (const float*)d_in[11];
  const float* W3_root = (const float*)d_in[12];
  const float* Wl1     = (const float*)d_in[13];
  const float* bl1     = (const float*)d_in[14];
  const float* Wl2     = (const float*)d_in[15];
  const float* bl2     = (const float*)d_in[16];
  const int* esrc = edge_idx;
  const int* edst = edge_idx + N_EDGES;

  char* ws = (char*)d_ws;
  size_t off = 0;
  auto alloc = [&](size_t bytes) {
    void* p = ws + off;
    off += (bytes + 255) & ~(size_t)255;
    return p;
  };
  int* row_ptr  = (int*)alloc((N_NODES + 1) * sizeof(int));
  int* bcnt     = (int*)alloc(NB * sizeof(int));
  int* boff     = (int*)alloc((NB + 1) * sizeof(int));
  int* bcursor  = (int*)alloc(NB * sizeof(int));
  int* csr_src  = (int*)alloc(N_EDGES * sizeof(int));
  us16* xb      = (us16*)alloc((size_t)NPAD * FDIM * sizeof(us16));
  us16* hA      = (us16*)alloc((size_t)NPAD * FDIM * sizeof(us16));
  us16* hB      = (us16*)alloc((size_t)NPAD * FDIM * sizeof(us16));
  us16* Wp      = (us16*)alloc(3 * 32768 * sizeof(us16));
  float* pooled = (float*)alloc(GDIM * FDIM * sizeof(float));
  // ebuf (6.4 MB, packed) aliases hA (25.6 MB): dead before layer-1 writes hA
  int* ebuf     = (int*)hA;

  hipMemsetAsync(bcnt, 0, NB * sizeof(int), stream);

  // prep: cast x, pack W, zero pooled, bucket-histogram edges (one kernel)
  k_prep<<<XB + 384 + 1 + NB, 256, 0, stream>>>(
      x, xb, W1_rel, W1_root, W2_rel, W2_root, W3_rel, W3_root, Wp, pooled,
      edst, bcnt);

  k_bscan<<<1, 256, 0, stream>>>(bcnt, boff, bcursor, row_ptr);
  k_bscatter<<<NB, 256, 0, stream>>>(esrc, edst, bcursor, ebuf);
  k_bucket_csr<<<NB, 256, 0, stream>>>(ebuf, boff, row_ptr, csr_src);

  int lgrid = NPAD / LROWS;                // 782
  k_layer<<<lgrid, 512, 0, stream>>>(xb, Wp,         b1_rel, row_ptr, csr_src, hA);
  k_layer<<<lgrid, 512, 0, stream>>>(hA, Wp + 32768, b2_rel, row_ptr, csr_src, hB);
  k_layer<<<lgrid, 512, 0, stream>>>(hB, Wp + 65536, b3_rel, row_ptr, csr_src, hA);

  int pool_grid = (N_NODES + POOL_CHUNK - 1) / POOL_CHUNK;
  k_pool_partial<<<pool_grid, 256, 0, stream>>>(hA, batch, pooled);
  k_head<<<GDIM, 128, 0, stream>>>(pooled, batch, Wl1, bl1, Wl2, bl2, (float*)d_out);
}

// Round 11
// 453.087 us; speedup vs baseline: 1.1239x; 1.1239x over previous
//
#include <hip/hip_runtime.h>

#define N_NODES 100000
#define NPAD    100096      // multiple of 128 so layer blocks need no row clamp
#define N_EDGES 1600000
#define FDIM 128
#define GDIM 64
#define CDIM 10

#define BSH   9
#define BSIZE 512           // nodes per bucket (r5-proven config)
#define NB    196           // ceil(N_NODES / BSIZE)
#define EPB   8192          // edges per block in bucket passes -> 196 blocks

typedef unsigned short us16;
typedef us16 usx4 __attribute__((ext_vector_type(4)));
typedef us16 usx8 __attribute__((ext_vector_type(8)));
typedef short bfrag __attribute__((ext_vector_type(8)));   // 8 bf16 = 4 VGPRs
typedef float f32x4 __attribute__((ext_vector_type(4)));

__device__ __forceinline__ float bf2f(us16 u) {
  return __uint_as_float(((unsigned)u) << 16);
}
__device__ __forceinline__ us16 f2bf(float f) {
  unsigned u = __float_as_uint(f);
  u += 0x7FFFu + ((u >> 16) & 1u);   // RNE
  return (us16)(u >> 16);
}

// ---------------- prep: cast x, pack W, zero pooled, bucket histogram ---------
// bcnt is zeroed by a memsetAsync BEFORE this kernel.
#define XB 6250            // N_NODES*FDIM/8/256 cast blocks
__global__ __launch_bounds__(256) void k_prep(
    const float* __restrict__ x, us16* __restrict__ xb,
    const float* __restrict__ Wrel1, const float* __restrict__ Wroot1,
    const float* __restrict__ Wrel2, const float* __restrict__ Wroot2,
    const float* __restrict__ Wrel3, const float* __restrict__ Wroot3,
    us16* __restrict__ Wp, float* __restrict__ pooled,
    const int* __restrict__ edst, int* __restrict__ bcnt) {
  int bx = blockIdx.x, tid = threadIdx.x;
  if (bx < XB) {
    size_t i = ((size_t)bx * 256 + tid) * 8;    // 8 floats per thread
    float4 a = *(const float4*)(x + i);
    float4 b = *(const float4*)(x + i + 4);
    usx8 o;
    o[0]=f2bf(a.x); o[1]=f2bf(a.y); o[2]=f2bf(a.z); o[3]=f2bf(a.w);
    o[4]=f2bf(b.x); o[5]=f2bf(b.y); o[6]=f2bf(b.z); o[7]=f2bf(b.w);
    *(usx8*)(xb + i) = o;
  } else if (bx < XB + 384) {
    int wb = bx - XB;             // 0..383
    int l = wb >> 7;              // layer
    const float* Wrel  = (l == 0) ? Wrel1  : (l == 1) ? Wrel2  : Wrel3;
    const float* Wroot = (l == 0) ? Wroot1 : (l == 1) ? Wroot2 : Wroot3;
    int idx = (wb & 127) * 256 + tid;   // 0..32767
    int k = idx >> 7;       // 0..255
    int c = idx & 127;      // output col
    float v = (k < 128) ? Wrel[c * 128 + k] : Wroot[c * 128 + k - 128];
    Wp[(size_t)l * 32768 + (((k >> 3) * 128 + c) << 3) + (k & 7)] = f2bf(v);
  } else if (bx == XB + 384) {
    for (int i = tid; i < GDIM * FDIM; i += 256) pooled[i] = 0.f;
  } else {
    // bucket histogram over edge chunk
    __shared__ int h[NB];
    int cb = bx - (XB + 385);
    for (int i = tid; i < NB; i += 256) h[i] = 0;
    __syncthreads();
    int s0 = cb * EPB;
    int e0 = s0 + EPB; if (e0 > N_EDGES) e0 = N_EDGES;
    for (int i = s0 + tid; i < e0; i += 256) atomicAdd(&h[edst[i] >> BSH], 1);
    __syncthreads();
    for (int i = tid; i < NB; i += 256)
      if (h[i]) atomicAdd(&bcnt[i], h[i]);
  }
}

// scan NB bucket counts -> offsets + cursors (single block)
__global__ void k_bscan(const int* __restrict__ bcnt, int* __restrict__ boff,
                        int* __restrict__ bcursor, int* __restrict__ row_ptr) {
  __shared__ int sm[256];
  int tid = threadIdx.x;
  int v = (tid < NB) ? bcnt[tid] : 0;
  sm[tid] = v;
  __syncthreads();
  for (int off = 1; off < 256; off <<= 1) {
    int t = (tid >= off) ? sm[tid - off] : 0;
    __syncthreads();
    sm[tid] += t;
    __syncthreads();
  }
  if (tid < NB) { int ex = sm[tid] - v; boff[tid] = ex; bcursor[tid] = ex; }
  if (tid == 0) { boff[NB] = N_EDGES; row_ptr[N_NODES] = N_EDGES; }
}

// Pass C: counting-sort edges into bucket-contiguous runs.
// Record packed as (src << 9) | dst_local  (src < 2^17 -> fits 26 bits).
__global__ __launch_bounds__(256) void k_bscatter(
    const int* __restrict__ src, const int* __restrict__ dst,
    int* __restrict__ bcursor, int* __restrict__ ebuf) {
  __shared__ int h[NB];
  __shared__ int base[NB];
  __shared__ int lc[NB];
  int tid = threadIdx.x;
  for (int i = tid; i < NB; i += 256) h[i] = 0;
  __syncthreads();
  int s0 = blockIdx.x * EPB;
  int e0 = s0 + EPB; if (e0 > N_EDGES) e0 = N_EDGES;
  for (int i = s0 + tid; i < e0; i += 256) atomicAdd(&h[dst[i] >> BSH], 1);
  __syncthreads();
  for (int i = tid; i < NB; i += 256) {
    base[i] = h[i] ? atomicAdd(&bcursor[i], h[i]) : 0;
    lc[i] = 0;
  }
  __syncthreads();
  for (int i = s0 + tid; i < e0; i += 256) {
    int d = dst[i];
    int b = d >> BSH;
    int lp = atomicAdd(&lc[b], 1);
    ebuf[base[b] + lp] = (src[i] << BSH) | (d & (BSIZE - 1));
  }
}

// Pass D: per-bucket histogram + Blelloch scan -> row_ptr, LDS-cursor scatter.
__global__ __launch_bounds__(256) void k_bucket_csr(
    const int* __restrict__ ebuf, const int* __restrict__ boff,
    int* __restrict__ row_ptr, int* __restrict__ csr_src) {
  __shared__ int hist[BSIZE];
  __shared__ int cur[BSIZE];
  int b = blockIdx.x, tid = threadIdx.x;
  int eoff = boff[b], ecnt = boff[b + 1] - eoff;
  int base = b * BSIZE;
  hist[tid] = 0; hist[tid + 256] = 0;
  __syncthreads();
  for (int i = tid; i < ecnt; i += 256)
    atomicAdd(&hist[ebuf[eoff + i] & (BSIZE - 1)], 1);
  __syncthreads();
  for (int d = 1; d < BSIZE; d <<= 1) {
    int idx = (tid + 1) * (d << 1) - 1;
    if (idx < BSIZE) hist[idx] += hist[idx - d];
    __syncthreads();
  }
  if (tid == 0) hist[BSIZE - 1] = 0;
  __syncthreads();
  for (int d = BSIZE >> 1; d >= 1; d >>= 1) {
    int idx = (tid + 1) * (d << 1) - 1;
    if (idx < BSIZE) {
      int t = hist[idx - d];
      hist[idx - d] = hist[idx];
      hist[idx] += t;
    }
    __syncthreads();
  }
  {
    int n0 = base + tid, n1 = base + tid + 256;
    if (n0 < N_NODES) row_ptr[n0] = eoff + hist[tid];
    if (n1 < N_NODES) row_ptr[n1] = eoff + hist[tid + 256];
    cur[tid] = hist[tid];
    cur[tid + 256] = hist[tid + 256];
  }
  __syncthreads();
  for (int i = tid; i < ecnt; i += 256) {
    int e = ebuf[eoff + i];
    int lp = atomicAdd(&cur[e & (BSIZE - 1)], 1);
    csr_src[eoff + lp] = e >> BSH;
  }
}

// ---------------- fused layer: gather-aggregate -> MFMA dual GEMM -------------
// out = relu(agg(hin) @ Wrel^T + hin @ Wroot^T + b).
// 512 threads / 128 rows per block.  If pooled != nullptr (last layer): skip
// the global store entirely and reduce relu outputs straight into pooled[g][c]
// (sorted batch -> 16-row wave window is nearly always one graph: shfl-reduce
// + 1 atomic per col; boundary waves fall back to per-element atomics).
#define ASTR 136
#define LROWS 128
__global__ __launch_bounds__(512) void k_layer(
    const us16* __restrict__ hin, const us16* __restrict__ Wp,
    const float* __restrict__ bias, const int* __restrict__ row_ptr,
    const int* __restrict__ csr_src, us16* __restrict__ out,
    const int* __restrict__ batch, float* __restrict__ pooled) {
  __shared__ us16 As[LROWS * ASTR];   // 34.8 KB
  int tid = threadIdx.x;
  int node0 = blockIdx.x * LROWS;
  int slot = tid >> 4;      // 0..31: node slot within round
  int lane16 = tid & 15;    // feature octet
  const us16* gbase = hin + lane16 * 8;

  // ---- phase 1: aggregate 128 nodes (4 rounds x 32 concurrent) ----
#pragma unroll 1
  for (int rnd = 0; rnd < 4; ++rnd) {
    int node = node0 + rnd * 32 + slot;
    float a0 = 0.f, a1 = 0.f, a2 = 0.f, a3 = 0.f;
    float a4 = 0.f, a5 = 0.f, a6 = 0.f, a7 = 0.f;
    if (node < N_NODES) {
      int s = row_ptr[node], e = row_ptr[node + 1];
      int p = s;
      for (; p + 4 <= e; p += 4) {
        int j0 = csr_src[p], j1 = csr_src[p + 1];
        int j2 = csr_src[p + 2], j3 = csr_src[p + 3];
        usx8 v0 = *(const usx8*)(gbase + (size_t)j0 * FDIM);
        usx8 v1 = *(const usx8*)(gbase + (size_t)j1 * FDIM);
        usx8 v2 = *(const usx8*)(gbase + (size_t)j2 * FDIM);
        usx8 v3 = *(const usx8*)(gbase + (size_t)j3 * FDIM);
        a0 += bf2f(v0[0]) + bf2f(v1[0]) + bf2f(v2[0]) + bf2f(v3[0]);
        a1 += bf2f(v0[1]) + bf2f(v1[1]) + bf2f(v2[1]) + bf2f(v3[1]);
        a2 += bf2f(v0[2]) + bf2f(v1[2]) + bf2f(v2[2]) + bf2f(v3[2]);
        a3 += bf2f(v0[3]) + bf2f(v1[3]) + bf2f(v2[3]) + bf2f(v3[3]);
        a4 += bf2f(v0[4]) + bf2f(v1[4]) + bf2f(v2[4]) + bf2f(v3[4]);
        a5 += bf2f(v0[5]) + bf2f(v1[5]) + bf2f(v2[5]) + bf2f(v3[5]);
        a6 += bf2f(v0[6]) + bf2f(v1[6]) + bf2f(v2[6]) + bf2f(v3[6]);
        a7 += bf2f(v0[7]) + bf2f(v1[7]) + bf2f(v2[7]) + bf2f(v3[7]);
      }
      for (; p < e; ++p) {
        int j = csr_src[p];
        usx8 v = *(const usx8*)(gbase + (size_t)j * FDIM);
        a0 += bf2f(v[0]); a1 += bf2f(v[1]); a2 += bf2f(v[2]); a3 += bf2f(v[3]);
        a4 += bf2f(v[4]); a5 += bf2f(v[5]); a6 += bf2f(v[6]); a7 += bf2f(v[7]);
      }
    }
    usx8 o;
    o[0] = f2bf(a0); o[1] = f2bf(a1); o[2] = f2bf(a2); o[3] = f2bf(a3);
    o[4] = f2bf(a4); o[5] = f2bf(a5); o[6] = f2bf(a6); o[7] = f2bf(a7);
    *(usx8*)&As[(rnd * 32 + slot) * ASTR + lane16 * 8] = o;
  }
  __syncthreads();

  // ---- phase 2: MFMA.  A agg-half from LDS, root-half from global (own rows),
  //      W b-frags straight from L1/L2.
  int wave = tid >> 6, lane = tid & 63;
  int m = lane & 15, quad = lane >> 4;
  size_t rowA = (size_t)(node0 + wave * 16 + m);
  const us16* baseH = hin + rowA * FDIM + quad * 8;
  const us16* aldsb = &As[(wave * 16 + m) * ASTR + quad * 8];
  f32x4 acc[8];
#pragma unroll
  for (int t = 0; t < 8; ++t) acc[t] = (f32x4){0.f, 0.f, 0.f, 0.f};

#pragma unroll 1
  for (int c = 0; c < 8; ++c) {
    bfrag a;
    if (c < 4) a = *(const bfrag*)(aldsb + c * 32);
    else       a = *(const bfrag*)(baseH + (c - 4) * 32);
    int kq = c * 4 + quad;
    const us16* wbase = Wp + (((size_t)kq * 128 + m) << 3);
#pragma unroll
    for (int t = 0; t < 8; ++t) {
      bfrag b = *(const bfrag*)(wbase + t * 128);   // 16 cols * 8 j
      acc[t] = __builtin_amdgcn_mfma_f32_16x16x32_bf16(a, b, acc[t], 0, 0, 0);
    }
  }
  // epilogue: D lane mapping col = lane&15 (within t-tile), row = quad*4 + i
  int w16 = node0 + wave * 16;
  int orow0 = w16 + quad * 4;
  if (pooled == nullptr) {
#pragma unroll
    for (int t = 0; t < 8; ++t) {
      int col = t * 16 + m;
      float bv = bias[col];
#pragma unroll
      for (int i = 0; i < 4; ++i) {
        int r = orow0 + i;
        if (r < N_NODES)
          out[(size_t)r * FDIM + col] = f2bf(fmaxf(acc[t][i] + bv, 0.f));
      }
    }
  } else {
    // fused mean-pool (sum phase): no global store of h3
    int rlast = w16 + 15;
    int gfirst = batch[(w16 < N_NODES) ? w16 : (N_NODES - 1)];
    int glast  = batch[(rlast < N_NODES) ? rlast : (N_NODES - 1)];
    bool uniform = (gfirst == glast) && (rlast < N_NODES);
    if (uniform) {
#pragma unroll
      for (int t = 0; t < 8; ++t) {
        int col = t * 16 + m;
        float bv = bias[col];
        float v = fmaxf(acc[t][0] + bv, 0.f) + fmaxf(acc[t][1] + bv, 0.f) +
                  fmaxf(acc[t][2] + bv, 0.f) + fmaxf(acc[t][3] + bv, 0.f);
        v += __shfl_xor(v, 16);
        v += __shfl_xor(v, 32);
        if (quad == 0) atomicAdd(&pooled[gfirst * FDIM + col], v);
      }
    } else {
      int g[4];
#pragma unroll
      for (int i = 0; i < 4; ++i) {
        int r = orow0 + i;
        g[i] = batch[(r < N_NODES) ? r : (N_NODES - 1)];
      }
#pragma unroll
      for (int t = 0; t < 8; ++t) {
        int col = t * 16 + m;
        float bv = bias[col];
#pragma unroll
        for (int i = 0; i < 4; ++i) {
          int r = orow0 + i;
          if (r < N_NODES)
            atomicAdd(&pooled[g[i] * FDIM + col], fmaxf(acc[t][i] + bv, 0.f));
        }
      }
    }
  }
}

// ---------------- MLP head + log_softmax (divides pooled sums by counts) ------
__global__ __launch_bounds__(128) void k_head(
    const float* __restrict__ pooled, const int* __restrict__ batch,
    const float* __restrict__ Wl1, const float* __restrict__ bl1,
    const float* __restrict__ Wl2, const float* __restrict__ bl2,
    float* __restrict__ out) {
  int g = blockIdx.x;
  __shared__ int sb[2];
  __shared__ float p[128];
  __shared__ float h1[64];
  __shared__ float logit[CDIM];
  if (threadIdx.x < 2) {
    int key = g + (int)threadIdx.x;
    int lo = 0, hi = N_NODES;
    while (lo < hi) {
      int mid = (lo + hi) >> 1;
      if (batch[mid] < key) lo = mid + 1; else hi = mid;
    }
    sb[threadIdx.x] = lo;
  }
  __syncthreads();
  float cnt = (float)(sb[1] - sb[0]);
  p[threadIdx.x] = pooled[g * FDIM + threadIdx.x] / fmaxf(cnt, 1.f);
  __syncthreads();
  if (threadIdx.x < 64) {
    float acc = bl1[threadIdx.x];
    for (int k = 0; k < 128; ++k) acc += p[k] * Wl1[threadIdx.x * 128 + k];
    h1[threadIdx.x] = fmaxf(acc, 0.f);
  }
  __syncthreads();
  if (threadIdx.x < CDIM) {
    float acc = bl2[threadIdx.x];
    for (int k = 0; k < 64; ++k) acc += h1[k] * Wl2[threadIdx.x * 64 + k];
    logit[threadIdx.x] = acc;
  }
  __syncthreads();
  if (threadIdx.x == 0) {
    float m = -1e30f;
    for (int c = 0; c < CDIM; ++c) m = fmaxf(m, logit[c]);
    float s = 0.f;
    for (int c = 0; c < CDIM; ++c) s += expf(logit[c] - m);
    float ls = logf(s);
    for (int c = 0; c < CDIM; ++c) out[g * CDIM + c] = logit[c] - m - ls;
  }
}

extern "C" void kernel_launch(void* const* d_in, const int* in_sizes, int n_in,
                              void* d_out, int out_size, void* d_ws, size_t ws_size,
                              hipStream_t stream) {
  const float* x      = (const float*)d_in[0];
  const int* edge_idx = (const int*)d_in[1];
  const int* batch    = (const int*)d_in[2];
  const float* W1_rel  = (const float*)d_in[4];
  const float* b1_rel  = (const float*)d_in[5];
  const float* W1_root = (const float*)d_in[6];
  const float* W2_rel  = (const float*)d_in[7];
  const float* b2_rel  = (const float*)d_in[8];
  const float* W2_root = (const float*)d_in[9];
  const float* W3_rel  = (const float*)d_in[10];
  const float* b3_rel  = (const float*)d_in[11];
  const float* W3_root = (const float*)d_in[12];
  const float* Wl1     = (const float*)d_in[13];
  const float* bl1     = (const float*)d_in[14];
  const float* Wl2     = (const float*)d_in[15];
  const float* bl2     = (const float*)d_in[16];
  const int* esrc = edge_idx;
  const int* edst = edge_idx + N_EDGES;

  char* ws = (char*)d_ws;
  size_t off = 0;
  auto alloc = [&](size_t bytes) {
    void* p = ws + off;
    off += (bytes + 255) & ~(size_t)255;
    return p;
  };
  int* row_ptr  = (int*)alloc((N_NODES + 1) * sizeof(int));
  int* bcnt     = (int*)alloc(NB * sizeof(int));
  int* boff     = (int*)alloc((NB + 1) * sizeof(int));
  int* bcursor  = (int*)alloc(NB * sizeof(int));
  int* csr_src  = (int*)alloc(N_EDGES * sizeof(int));
  us16* xb      = (us16*)alloc((size_t)NPAD * FDIM * sizeof(us16));
  us16* hA      = (us16*)alloc((size_t)NPAD * FDIM * sizeof(us16));
  us16* hB      = (us16*)alloc((size_t)NPAD * FDIM * sizeof(us16));
  us16* Wp      = (us16*)alloc(3 * 32768 * sizeof(us16));
  float* pooled = (float*)alloc(GDIM * FDIM * sizeof(float));
  // ebuf (6.4 MB, packed) aliases hA (25.6 MB): dead before layer-1 writes hA
  int* ebuf     = (int*)hA;

  hipMemsetAsync(bcnt, 0, NB * sizeof(int), stream);

  // prep: cast x, pack W, zero pooled, bucket-histogram edges (one kernel)
  k_prep<<<XB + 384 + 1 + NB, 256, 0, stream>>>(
      x, xb, W1_rel, W1_root, W2_rel, W2_root, W3_rel, W3_root, Wp, pooled,
      edst, bcnt);

  k_bscan<<<1, 256, 0, stream>>>(bcnt, boff, bcursor, row_ptr);
  k_bscatter<<<NB, 256, 0, stream>>>(esrc, edst, bcursor, ebuf);
  k_bucket_csr<<<NB, 256, 0, stream>>>(ebuf, boff, row_ptr, csr_src);

  int lgrid = NPAD / LROWS;                // 782
  k_layer<<<lgrid, 512, 0, stream>>>(xb, Wp,         b1_rel, row_ptr, csr_src,
                                     hA, batch, nullptr);
  k_layer<<<lgrid, 512, 0, stream>>>(hA, Wp + 32768, b2_rel, row_ptr, csr_src,
                                     hB, batch, nullptr);
  // layer 3: no h3 store — relu outputs reduced straight into pooled sums
  k_layer<<<lgrid, 512, 0, stream>>>(hB, Wp + 65536, b3_rel, row_ptr, csr_src,
                                     hA, batch, pooled);

  k_head<<<GDIM, 128, 0, stream>>>(pooled, batch, Wl1, bl1, Wl2, bl2, (float*)d_out);
}

// Round 12
// 418.365 us; speedup vs baseline: 1.2171x; 1.0830x over previous
//
#include <hip/hip_runtime.h>

#define N_NODES 100000
#define NPAD    100096      // multiple of 128 so layer blocks need no row clamp
#define N_EDGES 1600000
#define FDIM 128
#define GDIM 64
#define CDIM 10

#define BSH   9
#define BSIZE 512           // nodes per bucket
#define NB    196           // ceil(N_NODES / BSIZE)
#define EPB   8192          // edges per chunk in prep's histogram -> 196 chunks
#define EPB_C 6250          // edges per bscatter block -> 256 blocks exactly

typedef unsigned short us16;
typedef us16 usx4 __attribute__((ext_vector_type(4)));
typedef us16 usx8 __attribute__((ext_vector_type(8)));
typedef short bfrag __attribute__((ext_vector_type(8)));   // 8 bf16 = 4 VGPRs
typedef float f32x4 __attribute__((ext_vector_type(4)));

__device__ __forceinline__ float bf2f(us16 u) {
  return __uint_as_float(((unsigned)u) << 16);
}
__device__ __forceinline__ us16 f2bf(float f) {
  unsigned u = __float_as_uint(f);
  u += 0x7FFFu + ((u >> 16) & 1u);   // RNE
  return (us16)(u >> 16);
}

// ---------------- prep: cast x, pack W, zero pooled, bucket histogram ---------
// bcnt is zeroed by a memsetAsync BEFORE this kernel.
#define XB 6250            // N_NODES*FDIM/8/256 cast blocks
__global__ __launch_bounds__(256) void k_prep(
    const float* __restrict__ x, us16* __restrict__ xb,
    const float* __restrict__ Wrel1, const float* __restrict__ Wroot1,
    const float* __restrict__ Wrel2, const float* __restrict__ Wroot2,
    const float* __restrict__ Wrel3, const float* __restrict__ Wroot3,
    us16* __restrict__ Wp, float* __restrict__ pooled,
    const int* __restrict__ edst, int* __restrict__ bcnt) {
  int bx = blockIdx.x, tid = threadIdx.x;
  if (bx < XB) {
    size_t i = ((size_t)bx * 256 + tid) * 8;    // 8 floats per thread
    float4 a = *(const float4*)(x + i);
    float4 b = *(const float4*)(x + i + 4);
    usx8 o;
    o[0]=f2bf(a.x); o[1]=f2bf(a.y); o[2]=f2bf(a.z); o[3]=f2bf(a.w);
    o[4]=f2bf(b.x); o[5]=f2bf(b.y); o[6]=f2bf(b.z); o[7]=f2bf(b.w);
    *(usx8*)(xb + i) = o;
  } else if (bx < XB + 384) {
    int wb = bx - XB;             // 0..383
    int l = wb >> 7;              // layer
    const float* Wrel  = (l == 0) ? Wrel1  : (l == 1) ? Wrel2  : Wrel3;
    const float* Wroot = (l == 0) ? Wroot1 : (l == 1) ? Wroot2 : Wroot3;
    int idx = (wb & 127) * 256 + tid;   // 0..32767
    int k = idx >> 7;       // 0..255
    int c = idx & 127;      // output col
    float v = (k < 128) ? Wrel[c * 128 + k] : Wroot[c * 128 + k - 128];
    Wp[(size_t)l * 32768 + (((k >> 3) * 128 + c) << 3) + (k & 7)] = f2bf(v);
  } else if (bx == XB + 384) {
    for (int i = tid; i < GDIM * FDIM; i += 256) pooled[i] = 0.f;
  } else {
    // bucket histogram over edge chunk
    __shared__ int h[NB];
    int cb = bx - (XB + 385);
    for (int i = tid; i < NB; i += 256) h[i] = 0;
    __syncthreads();
    int s0 = cb * EPB;
    int e0 = s0 + EPB; if (e0 > N_EDGES) e0 = N_EDGES;
    for (int i = s0 + tid; i < e0; i += 256) atomicAdd(&h[edst[i] >> BSH], 1);
    __syncthreads();
    for (int i = tid; i < NB; i += 256)
      if (h[i]) atomicAdd(&bcnt[i], h[i]);
  }
}

// scan NB bucket counts -> offsets + cursors (single block)
__global__ void k_bscan(const int* __restrict__ bcnt, int* __restrict__ boff,
                        int* __restrict__ bcursor, int* __restrict__ row_ptr) {
  __shared__ int sm[256];
  int tid = threadIdx.x;
  int v = (tid < NB) ? bcnt[tid] : 0;
  sm[tid] = v;
  __syncthreads();
  for (int off = 1; off < 256; off <<= 1) {
    int t = (tid >= off) ? sm[tid - off] : 0;
    __syncthreads();
    sm[tid] += t;
    __syncthreads();
  }
  if (tid < NB) { int ex = sm[tid] - v; boff[tid] = ex; bcursor[tid] = ex; }
  if (tid == 0) { boff[NB] = N_EDGES; row_ptr[N_NODES] = N_EDGES; }
}

// Pass C: counting-sort edges into bucket-contiguous runs.
// 1024 threads x 256 blocks: 4x the in-flight waves of the old 256x196 config
// (this pass is latency/occupancy-bound, not BW-bound).
// Record packed as (src << 9) | dst_local  (src < 2^17 -> fits 26 bits).
__global__ __launch_bounds__(1024) void k_bscatter(
    const int* __restrict__ src, const int* __restrict__ dst,
    int* __restrict__ bcursor, int* __restrict__ ebuf) {
  __shared__ int h[NB];
  __shared__ int base[NB];
  __shared__ int lc[NB];
  int tid = threadIdx.x;
  for (int i = tid; i < NB; i += 1024) h[i] = 0;
  __syncthreads();
  int s0 = blockIdx.x * EPB_C;
  int e0 = s0 + EPB_C; if (e0 > N_EDGES) e0 = N_EDGES;
  for (int i = s0 + tid; i < e0; i += 1024) atomicAdd(&h[dst[i] >> BSH], 1);
  __syncthreads();
  for (int i = tid; i < NB; i += 1024) {
    base[i] = h[i] ? atomicAdd(&bcursor[i], h[i]) : 0;
    lc[i] = 0;
  }
  __syncthreads();
  for (int i = s0 + tid; i < e0; i += 1024) {
    int d = dst[i];
    int b = d >> BSH;
    int lp = atomicAdd(&lc[b], 1);
    ebuf[base[b] + lp] = (src[i] << BSH) | (d & (BSIZE - 1));
  }
}

// Pass D: per-bucket histogram + Blelloch scan -> row_ptr, LDS-cursor scatter.
// 1024 threads: deeper latency hiding on the scattered csr_src stores.
__global__ __launch_bounds__(1024) void k_bucket_csr(
    const int* __restrict__ ebuf, const int* __restrict__ boff,
    int* __restrict__ row_ptr, int* __restrict__ csr_src) {
  __shared__ int hist[BSIZE];
  __shared__ int cur[BSIZE];
  int b = blockIdx.x, tid = threadIdx.x;
  int eoff = boff[b], ecnt = boff[b + 1] - eoff;
  int base = b * BSIZE;
  if (tid < BSIZE) hist[tid] = 0;
  __syncthreads();
  for (int i = tid; i < ecnt; i += 1024)
    atomicAdd(&hist[ebuf[eoff + i] & (BSIZE - 1)], 1);
  __syncthreads();
  for (int d = 1; d < BSIZE; d <<= 1) {
    int idx = (tid + 1) * (d << 1) - 1;
    if (idx < BSIZE) hist[idx] += hist[idx - d];
    __syncthreads();
  }
  if (tid == 0) hist[BSIZE - 1] = 0;
  __syncthreads();
  for (int d = BSIZE >> 1; d >= 1; d >>= 1) {
    int idx = (tid + 1) * (d << 1) - 1;
    if (idx < BSIZE) {
      int t = hist[idx - d];
      hist[idx - d] = hist[idx];
      hist[idx] += t;
    }
    __syncthreads();
  }
  if (tid < BSIZE) {
    int node = base + tid;
    if (node < N_NODES) row_ptr[node] = eoff + hist[tid];
    cur[tid] = hist[tid];
  }
  __syncthreads();
  for (int i = tid; i < ecnt; i += 1024) {
    int e = ebuf[eoff + i];
    int lp = atomicAdd(&cur[e & (BSIZE - 1)], 1);
    csr_src[eoff + lp] = e >> BSH;
  }
}

// ---------------- fused layer: gather-aggregate -> MFMA dual GEMM -------------
// out = relu(agg(hin) @ Wrel^T + hin @ Wroot^T + b).
// 512 threads / 128 rows per block.  If pooled != nullptr (last layer): skip
// the global store entirely and reduce relu outputs straight into pooled[g][c].
#define ASTR 136
#define LROWS 128
__global__ __launch_bounds__(512) void k_layer(
    const us16* __restrict__ hin, const us16* __restrict__ Wp,
    const float* __restrict__ bias, const int* __restrict__ row_ptr,
    const int* __restrict__ csr_src, us16* __restrict__ out,
    const int* __restrict__ batch, float* __restrict__ pooled) {
  __shared__ us16 As[LROWS * ASTR];   // 34.8 KB
  int tid = threadIdx.x;
  int node0 = blockIdx.x * LROWS;
  int slot = tid >> 4;      // 0..31: node slot within round
  int lane16 = tid & 15;    // feature octet
  const us16* gbase = hin + lane16 * 8;

  // ---- phase 1: aggregate 128 nodes (4 rounds x 32 concurrent) ----
#pragma unroll 1
  for (int rnd = 0; rnd < 4; ++rnd) {
    int node = node0 + rnd * 32 + slot;
    float a0 = 0.f, a1 = 0.f, a2 = 0.f, a3 = 0.f;
    float a4 = 0.f, a5 = 0.f, a6 = 0.f, a7 = 0.f;
    if (node < N_NODES) {
      int s = row_ptr[node], e = row_ptr[node + 1];
      int p = s;
      for (; p + 4 <= e; p += 4) {
        int j0 = csr_src[p], j1 = csr_src[p + 1];
        int j2 = csr_src[p + 2], j3 = csr_src[p + 3];
        usx8 v0 = *(const usx8*)(gbase + (size_t)j0 * FDIM);
        usx8 v1 = *(const usx8*)(gbase + (size_t)j1 * FDIM);
        usx8 v2 = *(const usx8*)(gbase + (size_t)j2 * FDIM);
        usx8 v3 = *(const usx8*)(gbase + (size_t)j3 * FDIM);
        a0 += bf2f(v0[0]) + bf2f(v1[0]) + bf2f(v2[0]) + bf2f(v3[0]);
        a1 += bf2f(v0[1]) + bf2f(v1[1]) + bf2f(v2[1]) + bf2f(v3[1]);
        a2 += bf2f(v0[2]) + bf2f(v1[2]) + bf2f(v2[2]) + bf2f(v3[2]);
        a3 += bf2f(v0[3]) + bf2f(v1[3]) + bf2f(v2[3]) + bf2f(v3[3]);
        a4 += bf2f(v0[4]) + bf2f(v1[4]) + bf2f(v2[4]) + bf2f(v3[4]);
        a5 += bf2f(v0[5]) + bf2f(v1[5]) + bf2f(v2[5]) + bf2f(v3[5]);
        a6 += bf2f(v0[6]) + bf2f(v1[6]) + bf2f(v2[6]) + bf2f(v3[6]);
        a7 += bf2f(v0[7]) + bf2f(v1[7]) + bf2f(v2[7]) + bf2f(v3[7]);
      }
      for (; p < e; ++p) {
        int j = csr_src[p];
        usx8 v = *(const usx8*)(gbase + (size_t)j * FDIM);
        a0 += bf2f(v[0]); a1 += bf2f(v[1]); a2 += bf2f(v[2]); a3 += bf2f(v[3]);
        a4 += bf2f(v[4]); a5 += bf2f(v[5]); a6 += bf2f(v[6]); a7 += bf2f(v[7]);
      }
    }
    usx8 o;
    o[0] = f2bf(a0); o[1] = f2bf(a1); o[2] = f2bf(a2); o[3] = f2bf(a3);
    o[4] = f2bf(a4); o[5] = f2bf(a5); o[6] = f2bf(a6); o[7] = f2bf(a7);
    *(usx8*)&As[(rnd * 32 + slot) * ASTR + lane16 * 8] = o;
  }
  __syncthreads();

  // ---- phase 2: MFMA.  A agg-half from LDS, root-half from global (own rows),
  //      W b-frags straight from L1/L2.
  int wave = tid >> 6, lane = tid & 63;
  int m = lane & 15, quad = lane >> 4;
  size_t rowA = (size_t)(node0 + wave * 16 + m);
  const us16* baseH = hin + rowA * FDIM + quad * 8;
  const us16* aldsb = &As[(wave * 16 + m) * ASTR + quad * 8];
  f32x4 acc[8];
#pragma unroll
  for (int t = 0; t < 8; ++t) acc[t] = (f32x4){0.f, 0.f, 0.f, 0.f};

#pragma unroll 1
  for (int c = 0; c < 8; ++c) {
    bfrag a;
    if (c < 4) a = *(const bfrag*)(aldsb + c * 32);
    else       a = *(const bfrag*)(baseH + (c - 4) * 32);
    int kq = c * 4 + quad;
    const us16* wbase = Wp + (((size_t)kq * 128 + m) << 3);
#pragma unroll
    for (int t = 0; t < 8; ++t) {
      bfrag b = *(const bfrag*)(wbase + t * 128);   // 16 cols * 8 j
      acc[t] = __builtin_amdgcn_mfma_f32_16x16x32_bf16(a, b, acc[t], 0, 0, 0);
    }
  }
  // epilogue: D lane mapping col = lane&15 (within t-tile), row = quad*4 + i
  int w16 = node0 + wave * 16;
  int orow0 = w16 + quad * 4;
  if (pooled == nullptr) {
#pragma unroll
    for (int t = 0; t < 8; ++t) {
      int col = t * 16 + m;
      float bv = bias[col];
#pragma unroll
      for (int i = 0; i < 4; ++i) {
        int r = orow0 + i;
        if (r < N_NODES)
          out[(size_t)r * FDIM + col] = f2bf(fmaxf(acc[t][i] + bv, 0.f));
      }
    }
  } else {
    // fused mean-pool (sum phase): no global store of h3
    int rlast = w16 + 15;
    int gfirst = batch[(w16 < N_NODES) ? w16 : (N_NODES - 1)];
    int glast  = batch[(rlast < N_NODES) ? rlast : (N_NODES - 1)];
    bool uniform = (gfirst == glast) && (rlast < N_NODES);
    if (uniform) {
#pragma unroll
      for (int t = 0; t < 8; ++t) {
        int col = t * 16 + m;
        float bv = bias[col];
        float v = fmaxf(acc[t][0] + bv, 0.f) + fmaxf(acc[t][1] + bv, 0.f) +
                  fmaxf(acc[t][2] + bv, 0.f) + fmaxf(acc[t][3] + bv, 0.f);
        v += __shfl_xor(v, 16);
        v += __shfl_xor(v, 32);
        if (quad == 0) atomicAdd(&pooled[gfirst * FDIM + col], v);
      }
    } else {
      int g[4];
#pragma unroll
      for (int i = 0; i < 4; ++i) {
        int r = orow0 + i;
        g[i] = batch[(r < N_NODES) ? r : (N_NODES - 1)];
      }
#pragma unroll
      for (int t = 0; t < 8; ++t) {
        int col = t * 16 + m;
        float bv = bias[col];
#pragma unroll
        for (int i = 0; i < 4; ++i) {
          int r = orow0 + i;
          if (r < N_NODES)
            atomicAdd(&pooled[g[i] * FDIM + col], fmaxf(acc[t][i] + bv, 0.f));
        }
      }
    }
  }
}

// ---------------- MLP head + log_softmax (divides pooled sums by counts) ------
__global__ __launch_bounds__(128) void k_head(
    const float* __restrict__ pooled, const int* __restrict__ batch,
    const float* __restrict__ Wl1, const float* __restrict__ bl1,
    const float* __restrict__ Wl2, const float* __restrict__ bl2,
    float* __restrict__ out) {
  int g = blockIdx.x;
  __shared__ int sb[2];
  __shared__ float p[128];
  __shared__ float h1[64];
  __shared__ float logit[CDIM];
  if (threadIdx.x < 2) {
    int key = g + (int)threadIdx.x;
    int lo = 0, hi = N_NODES;
    while (lo < hi) {
      int mid = (lo + hi) >> 1;
      if (batch[mid] < key) lo = mid + 1; else hi = mid;
    }
    sb[threadIdx.x] = lo;
  }
  __syncthreads();
  float cnt = (float)(sb[1] - sb[0]);
  p[threadIdx.x] = pooled[g * FDIM + threadIdx.x] / fmaxf(cnt, 1.f);
  __syncthreads();
  if (threadIdx.x < 64) {
    float acc = bl1[threadIdx.x];
    for (int k = 0; k < 128; ++k) acc += p[k] * Wl1[threadIdx.x * 128 + k];
    h1[threadIdx.x] = fmaxf(acc, 0.f);
  }
  __syncthreads();
  if (threadIdx.x < CDIM) {
    float acc = bl2[threadIdx.x];
    for (int k = 0; k < 64; ++k) acc += h1[k] * Wl2[threadIdx.x * 64 + k];
    logit[threadIdx.x] = acc;
  }
  __syncthreads();
  if (threadIdx.x == 0) {
    float m = -1e30f;
    for (int c = 0; c < CDIM; ++c) m = fmaxf(m, logit[c]);
    float s = 0.f;
    for (int c = 0; c < CDIM; ++c) s += expf(logit[c] - m);
    float ls = logf(s);
    for (int c = 0; c < CDIM; ++c) out[g * CDIM + c] = logit[c] - m - ls;
  }
}

extern "C" void kernel_launch(void* const* d_in, const int* in_sizes, int n_in,
                              void* d_out, int out_size, void* d_ws, size_t ws_size,
                              hipStream_t stream) {
  const float* x      = (const float*)d_in[0];
  const int* edge_idx = (const int*)d_in[1];
  const int* batch    = (const int*)d_in[2];
  const float* W1_rel  = (const float*)d_in[4];
  const float* b1_rel  = (const float*)d_in[5];
  const float* W1_root = (const float*)d_in[6];
  const float* W2_rel  = (const float*)d_in[7];
  const float* b2_rel  = (const float*)d_in[8];
  const float* W2_root = (const float*)d_in[9];
  const float* W3_rel  = (const float*)d_in[10];
  const float* b3_rel  = (const float*)d_in[11];
  const float* W3_root = (const float*)d_in[12];
  const float* Wl1     = (const float*)d_in[13];
  const float* bl1     = (const float*)d_in[14];
  const float* Wl2     = (const float*)d_in[15];
  const float* bl2     = (const float*)d_in[16];
  const int* esrc = edge_idx;
  const int* edst = edge_idx + N_EDGES;

  char* ws = (char*)d_ws;
  size_t off = 0;
  auto alloc = [&](size_t bytes) {
    void* p = ws + off;
    off += (bytes + 255) & ~(size_t)255;
    return p;
  };
  int* row_ptr  = (int*)alloc((N_NODES + 1) * sizeof(int));
  int* bcnt     = (int*)alloc(NB * sizeof(int));
  int* boff     = (int*)alloc((NB + 1) * sizeof(int));
  int* bcursor  = (int*)alloc(NB * sizeof(int));
  int* csr_src  = (int*)alloc(N_EDGES * sizeof(int));
  us16* xb      = (us16*)alloc((size_t)NPAD * FDIM * sizeof(us16));
  us16* hA      = (us16*)alloc((size_t)NPAD * FDIM * sizeof(us16));
  us16* hB      = (us16*)alloc((size_t)NPAD * FDIM * sizeof(us16));
  us16* Wp      = (us16*)alloc(3 * 32768 * sizeof(us16));
  float* pooled = (float*)alloc(GDIM * FDIM * sizeof(float));
  // ebuf (6.4 MB, packed) aliases hA (25.6 MB): dead before layer-1 writes hA
  int* ebuf     = (int*)hA;

  hipMemsetAsync(bcnt, 0, NB * sizeof(int), stream);

  // prep: cast x, pack W, zero pooled, bucket-histogram edges (one kernel)
  k_prep<<<XB + 384 + 1 + NB, 256, 0, stream>>>(
      x, xb, W1_rel, W1_root, W2_rel, W2_root, W3_rel, W3_root, Wp, pooled,
      edst, bcnt);

  k_bscan<<<1, 256, 0, stream>>>(bcnt, boff, bcursor, row_ptr);
  k_bscatter<<<(N_EDGES + EPB_C - 1) / EPB_C, 1024, 0, stream>>>(
      esrc, edst, bcursor, ebuf);
  k_bucket_csr<<<NB, 1024, 0, stream>>>(ebuf, boff, row_ptr, csr_src);

  int lgrid = NPAD / LROWS;                // 782
  k_layer<<<lgrid, 512, 0, stream>>>(xb, Wp,         b1_rel, row_ptr, csr_src,
                                     hA, batch, nullptr);
  k_layer<<<lgrid, 512, 0, stream>>>(hA, Wp + 32768, b2_rel, row_ptr, csr_src,
                                     hB, batch, nullptr);
  // layer 3: no h3 store — relu outputs reduced straight into pooled sums
  k_layer<<<lgrid, 512, 0, stream>>>(hB, Wp + 65536, b3_rel, row_ptr, csr_src,
                                     hA, batch, pooled);

  k_head<<<GDIM, 128, 0, stream>>>(pooled, batch, Wl1, bl1, Wl2, bl2, (float*)d_out);
}